// Round 6
// baseline (15.265 us; speedup 1.0000x reference)
//
#include <hip/hip_runtime.h>

namespace {
constexpr int NNODES = 128;
constexpr int NEDGES = 1024;
constexpr float PI_F = 3.14159265358979323846f;
}

// ---------------------------------------------------------------------------
// Kernel 1: coalesced row-major sweep of Ri/Ro (each element read once).
// Columns are (scaled) one-hot: exactly one nonzero per column per matrix.
// Writes compact per-edge arrays: receiver/sender index + value.
// grid (4 e-strips, 8 m-groups) x 256 threads.
// ---------------------------------------------------------------------------
__global__ __launch_bounds__(256)
void edge_extract(const float* __restrict__ Ri,
                  const float* __restrict__ Ro,
                  int*   __restrict__ eR,  float* __restrict__ eRV,
                  int*   __restrict__ eS,  float* __restrict__ eSV)
{
    const int e  = blockIdx.x * 256 + threadIdx.x;
    const int m0 = blockIdx.y * 16;
    float ri[16], ro[16];
    #pragma unroll
    for (int j = 0; j < 16; ++j) {
        ri[j] = Ri[(m0 + j) * NEDGES + e];
        ro[j] = Ro[(m0 + j) * NEDGES + e];
    }
    #pragma unroll
    for (int j = 0; j < 16; ++j) {
        if (ri[j] != 0.f) { eR[e] = m0 + j; eRV[e] = ri[j]; }
        if (ro[j] != 0.f) { eS[e] = m0 + j; eSV[e] = ro[j]; }
    }
}

// ---------------------------------------------------------------------------
// Kernel 2: one block per node. Reads only the compact edge arrays (20 KB,
// coalesced) + scattered X rows for incident edges (~16 lines).
//   contribution p = eRecvV[e] * w[e] * eSendV[e]
//   mi[k] += p * X[eSend[e],k]   if eRecv[e]==n
//   mo[k] += p * X[eRecv[e],k]   if eSend[e]==n
// Then butterfly-reduce 10 angles, and simulate the two disconnected
// sub-circuits: wave 0 -> A (qubits 0..7, 256 amps: 4 regs x 64 lanes),
// wave 1 -> B (qubits 8,9,10,11,13,14, 64 amps). Qubit 12 dropped.
// A bit map: reg bit0=q0, reg bit1=q1, lane bit (q-2) = qubit q (q=2..7).
// B bit map: lane bits {0..5} = qubits {8,9,10,11,13,14}.
// ---------------------------------------------------------------------------
__global__ __launch_bounds__(256)
void node_circuit(const float* __restrict__ X,
                  const float* __restrict__ ew,
                  const int*   __restrict__ eR,  const float* __restrict__ eRV,
                  const int*   __restrict__ eS,  const float* __restrict__ eSV,
                  const float* __restrict__ theta,
                  float* __restrict__ out)
{
    __shared__ float sang[4][10];
    const int n = blockIdx.x, tid = threadIdx.x;
    const int lane = tid & 63, wid = tid >> 6;

    // ---- per-edge contributions (coalesced array reads) ----
    float acc[10];
    #pragma unroll
    for (int k = 0; k < 10; ++k) acc[k] = 0.f;
    #pragma unroll
    for (int j = 0; j < 4; ++j) {
        const int e = tid + j * 256;
        const int r = eR[e], s = eS[e];
        const float p = eRV[e] * ew[e] * eSV[e];
        if (r == n) {
            #pragma unroll
            for (int k = 0; k < 5; ++k) acc[k] = fmaf(p, X[s * 5 + k], acc[k]);
        }
        if (s == n) {
            #pragma unroll
            for (int k = 0; k < 5; ++k) acc[5 + k] = fmaf(p, X[r * 5 + k], acc[5 + k]);
        }
    }
    #pragma unroll
    for (int m = 1; m < 64; m <<= 1) {
        #pragma unroll
        for (int k = 0; k < 10; ++k) acc[k] += __shfl_xor(acc[k], m, 64);
    }
    if (lane == 0) {
        #pragma unroll
        for (int k = 0; k < 10; ++k) sang[wid][k] = acc[k];
    }
    __syncthreads();
    if (wid >= 2) return;

    float c_, s_, t_, v0, v1, v2, v3;
#define CS(i)        __sincosf(0.5f * theta[i], &s_, &c_)

    if (wid == 0) {
        // ---- angles: M[0..7] = mi[0..4], mo[0..2] ----
        float v[8];
        #pragma unroll
        for (int k = 0; k < 8; ++k)
            v[k] = sang[0][k] + sang[1][k] + sang[2][k] + sang[3][k];

        // ================= circuit A (qubits 0..7) =================
        float ic[8], is[8];
        #pragma unroll
        for (int q = 0; q < 8; ++q) __sincosf(0.5f * v[q], &is[q], &ic[q]);

        float lp = 1.f;
        #pragma unroll
        for (int q = 2; q < 8; ++q) lp *= ((lane >> (q - 2)) & 1) ? is[q] : ic[q];
        float r0 = lp * ic[0] * ic[1];
        float r1 = lp * is[0] * ic[1];
        float r2 = lp * ic[0] * is[1];
        float r3 = lp * is[0] * is[1];

#define RY_REG0      { t_ = r0; r0 = c_*t_ - s_*r1; r1 = fmaf(s_, t_, c_*r1); \
                       t_ = r2; r2 = c_*t_ - s_*r3; r3 = fmaf(s_, t_, c_*r3); }
#define RY_REG1      { t_ = r0; r0 = c_*t_ - s_*r2; r2 = fmaf(s_, t_, c_*r2); \
                       t_ = r1; r1 = c_*t_ - s_*r3; r3 = fmaf(s_, t_, c_*r3); }
#define RY_LANE_A(sh){ const float sg = ((lane >> (sh)) & 1) ? s_ : -s_;      \
                       v0 = __shfl_xor(r0, 1 << (sh), 64);                    \
                       v1 = __shfl_xor(r1, 1 << (sh), 64);                    \
                       v2 = __shfl_xor(r2, 1 << (sh), 64);                    \
                       v3 = __shfl_xor(r3, 1 << (sh), 64);                    \
                       r0 = fmaf(c_, r0, sg*v0); r1 = fmaf(c_, r1, sg*v1);    \
                       r2 = fmaf(c_, r2, sg*v2); r3 = fmaf(c_, r3, sg*v3); }
#define CX_LL_A(csh, tsh) { const bool p = (lane >> (csh)) & 1;               \
                       v0 = __shfl_xor(r0, 1 << (tsh), 64);                   \
                       v1 = __shfl_xor(r1, 1 << (tsh), 64);                   \
                       v2 = __shfl_xor(r2, 1 << (tsh), 64);                   \
                       v3 = __shfl_xor(r3, 1 << (tsh), 64);                   \
                       if (p) { r0 = v0; r1 = v1; r2 = v2; r3 = v3; } }

        CS(0);  RY_REG0;                     // R t0 q0
        CS(1);  RY_REG1;                     // R t1 q1
        t_ = r1; r1 = r3; r3 = t_;           // C(0->1): ctrl reg0, tgt reg1
        CS(2);  RY_LANE_A(0);                // R t2 q2
        CS(3);  RY_LANE_A(1);                // R t3 q3
        CX_LL_A(1, 0);                       // C(3->2)
        CS(4);  RY_LANE_A(2);                // R t4 q4
        CS(5);  RY_LANE_A(3);                // R t5 q5
        CX_LL_A(2, 3);                       // C(4->5)
        CS(6);  RY_LANE_A(4);                // R t6 q6
        CS(7);  RY_LANE_A(5);                // R t7 q7
        CX_LL_A(5, 4);                       // C(7->6)
        CS(15); RY_REG1;                     // R t15 q1
        CS(16); RY_LANE_A(0);                // R t16 q2
        r2 = __shfl_xor(r2, 1, 64);          // C(1->2): ctrl reg1, tgt lane0
        r3 = __shfl_xor(r3, 1, 64);
        CS(14); RY_LANE_A(3);                // R t14 q5
        CS(15); RY_LANE_A(4);                // R t15 q6
        CX_LL_A(4, 3);                       // C(6->5)
        CS(19); RY_LANE_A(0);                // R t19 q2
        CS(20); RY_LANE_A(3);                // R t20 q5
        CX_LL_A(0, 3);                       // C(2->5)
        CS(23); RY_LANE_A(3);                // R t23 q5
        CS(25); RY_REG0;                     // R t25 q0
        CS(26); RY_LANE_A(3);                // R t26 q5
        r1 = __shfl_xor(r1, 8, 64);          // C(0->5): ctrl reg0, tgt lane3
        r3 = __shfl_xor(r3, 8, 64);
        CS(29); RY_LANE_A(3);                // R t29 q5

        float zA = (r0*r0 + r1*r1 + r2*r2 + r3*r3) * (((lane >> 3) & 1) ? -1.f : 1.f);
        #pragma unroll
        for (int m = 1; m < 64; m <<= 1) zA += __shfl_xor(zA, m, 64);
        if (lane == 0) out[n * 2 + 0] = PI_F * (1.f - zA);
    } else {
        // ---- angles: M[8] = mo[3], M[9] = mo[4]; M[10..14] = X[n,:] ----
        const float m8 = sang[0][8] + sang[1][8] + sang[2][8] + sang[3][8];
        const float m9 = sang[0][9] + sang[1][9] + sang[2][9] + sang[3][9];

        // ================= circuit B (qubits 8,9,10,11,13,14) =================
        float c8, s8, c9, s9, c10, s10, c11, s11, c13, s13, c14, s14;
        __sincosf(0.5f * m8,         &s8,  &c8);   // q8  = mo[3]
        __sincosf(0.5f * m9,         &s9,  &c9);   // q9  = mo[4]
        __sincosf(0.5f * X[n*5 + 0], &s10, &c10);  // q10 = X[n,0]
        __sincosf(0.5f * X[n*5 + 1], &s11, &c11);  // q11 = X[n,1]
        __sincosf(0.5f * X[n*5 + 3], &s13, &c13);  // q13 = X[n,3]
        __sincosf(0.5f * X[n*5 + 4], &s14, &c14);  // q14 = X[n,4]

        float b = ((lane >> 0) & 1) ? s8  : c8;
        b      *= ((lane >> 1) & 1) ? s9  : c9;
        b      *= ((lane >> 2) & 1) ? s10 : c10;
        b      *= ((lane >> 3) & 1) ? s11 : c11;
        b      *= ((lane >> 4) & 1) ? s13 : c13;
        b      *= ((lane >> 5) & 1) ? s14 : c14;

#define RY_B(sh)     { const float sg = ((lane >> (sh)) & 1) ? s_ : -s_;      \
                       v0 = __shfl_xor(b, 1 << (sh), 64);                     \
                       b = fmaf(c_, b, sg*v0); }
#define CX_B(csh, tsh) { v0 = __shfl_xor(b, 1 << (tsh), 64);                  \
                       if ((lane >> (csh)) & 1) b = v0; }

        CS(8);  RY_B(0);                     // R t8  q8
        CS(9);  RY_B(1);                     // R t9  q9
        CX_B(0, 1);                          // C(8->9)
        CS(10); RY_B(2);                     // R t10 q10
        CS(11); RY_B(3);                     // R t11 q11
        CX_B(3, 2);                          // C(11->10)
        CS(13); RY_B(4);                     // R t13 q13
        CX_B(0, 1);                          // C(8->9)
        CS(14); RY_B(5);                     // R t14 q14
        CS(16); RY_B(1);                     // R t16 q9
        CS(17); RY_B(2);                     // R t17 q10
        CX_B(1, 2);                          // C(9->10)
        CS(18); RY_B(4);                     // R t18 q13
        CS(19); RY_B(5);                     // R t19 q14
        CX_B(1, 2);                          // C(9->10)
        CS(21); RY_B(2);                     // R t21 q10
        CS(22); RY_B(4);                     // R t22 q13
        CX_B(4, 2);                          // C(13->10)
        CS(24); RY_B(2);                     // R t24 q10
        CS(27); RY_B(2);                     // R t27 q10
        CS(28); RY_B(5);                     // R t28 q14
        CX_B(5, 2);                          // C(14->10)
        CS(30); RY_B(2);                     // R t30 q10

        float zB = (b * b) * (((lane >> 2) & 1) ? -1.f : 1.f);
        #pragma unroll
        for (int m = 1; m < 64; m <<= 1) zB += __shfl_xor(zB, m, 64);
        if (lane == 0) out[n * 2 + 1] = PI_F * (1.f - zB);
    }
#undef CS
#undef RY_REG0
#undef RY_REG1
#undef RY_LANE_A
#undef CX_LL_A
#undef RY_B
#undef CX_B
}

extern "C" void kernel_launch(void* const* d_in, const int* in_sizes, int n_in,
                              void* d_out, int out_size, void* d_ws, size_t ws_size,
                              hipStream_t stream) {
    (void)in_sizes; (void)n_in; (void)ws_size; (void)out_size;
    const float* X     = (const float*)d_in[0];
    const float* ew    = (const float*)d_in[1];
    const float* Ri    = (const float*)d_in[2];
    const float* Ro    = (const float*)d_in[3];
    const float* theta = (const float*)d_in[4];
    float* out = (float*)d_out;

    // d_ws layout: eR[1024] int | eRV[1024] float | eS[1024] int | eSV[1024] float
    char* ws = (char*)d_ws;
    int*   eR  = (int*)  (ws);
    float* eRV = (float*)(ws + 4096);
    int*   eS  = (int*)  (ws + 8192);
    float* eSV = (float*)(ws + 12288);

    edge_extract<<<dim3(4, 8), 256, 0, stream>>>(Ri, Ro, eR, eRV, eS, eSV);
    node_circuit<<<NNODES, 256, 0, stream>>>(X, ew, eR, eRV, eS, eSV, theta, out);
}

// Round 7
// 13.679 us; speedup vs baseline: 1.1159x; 1.1159x over previous
//
#include <hip/hip_runtime.h>

namespace {
constexpr int NNODES = 128;
constexpr int NEDGES = 1024;
constexpr int CAP    = 96;     // max incident edges per node per direction
constexpr int NIT    = 12;     // static batched scan: NIT*4 waves = 48 slots
constexpr float PI_F = 3.14159265358979323846f;
}

// ---------------------------------------------------------------------------
// Fully fused, ONE dispatch (dispatch count is the dominant cost at this
// scale: measured fixed replay overhead ~10.6us + ~2.2us/dispatch).
// One block per node. Ri/Ro columns are exact one-hots.
//  phase 1: scan own Ri/Ro rows (coalesced) -> incident edge lists
//  phase 2: statically-batched predicated column scans (one memory
//           round-trip) -> sender o(e) / receiver r(e) + column value
//  phase 3: angles M[15] via LDS atomics (few ops, contention trivial)
//  phase 4: wave 0 simulates sub-circuit A (qubits 0..7, 256 amps),
//           wave 1 simulates sub-circuit B (qubits 8,9,10,11,13,14, 64 amps).
//           Qubit 12 is unentangled & unmeasured -> dropped.
// A bit map: reg bit0=q0, reg bit1=q1, lane bit (q-2) = qubit q (q=2..7).
// B bit map: lane bits {0..5} = qubits {8,9,10,11,13,14}.
// ---------------------------------------------------------------------------
__global__ __launch_bounds__(256)
void nodenet_fused(const float* __restrict__ X,
                   const float* __restrict__ ew,
                   const float* __restrict__ Ri,
                   const float* __restrict__ Ro,
                   const float* __restrict__ theta,
                   float* __restrict__ out)
{
    __shared__ float Xs[NNODES * 5];
    __shared__ float Mang[15];
    __shared__ int   cin, cout;
    __shared__ int   inE[CAP];  __shared__ float inW[CAP];
    __shared__ int   inO[CAP];  __shared__ float inV[CAP];
    __shared__ int   outE[CAP]; __shared__ float outW[CAP];
    __shared__ int   outR[CAP]; __shared__ float outV[CAP];

    const int n = blockIdx.x, tid = threadIdx.x;
    const int lane = tid & 63, wid = tid >> 6;

    // ---- phase 0: stage X, init angle accumulators ----
    for (int i = tid; i < NNODES * 5; i += 256) Xs[i] = X[i];
    if (tid < 10) Mang[tid] = 0.f;
    else if (tid < 15) Mang[tid] = X[n * 5 + (tid - 10)];
    if (tid == 0) { cin = 0; cout = 0; }
    __syncthreads();

    // ---- phase 1: scan own rows for incident edges (coalesced) ----
    #pragma unroll
    for (int j = 0; j < 4; ++j) {
        const int e = tid + j * 256;
        const float riv = Ri[n * NEDGES + e];
        const float rov = Ro[n * NEDGES + e];
        if (riv != 0.f) {
            const int idx = atomicAdd(&cin, 1);
            if (idx < CAP) { inE[idx] = e; inW[idx] = riv * ew[e]; }
        }
        if (rov != 0.f) {
            const int idx = atomicAdd(&cout, 1);
            if (idx < CAP) { outE[idx] = e; outW[idx] = rov * ew[e]; }
        }
    }
    __syncthreads();

    const int ci = min(cin, CAP), co = min(cout, CAP);
    const int total = ci + co;

    // ---- phase 2: batched column scans (48 slots, one round-trip) ----
    float va[NIT], vb[NIT];
    #pragma unroll
    for (int it = 0; it < NIT; ++it) {
        const int t = wid + it * 4;
        int e = 0;
        const float* col = Ri;             // dummy default (valid memory)
        if (t < ci)         { e = inE[t];       col = Ro; }
        else if (t < total) { e = outE[t - ci]; col = Ri; }
        va[it] = col[lane * NEDGES + e];
        vb[it] = col[(lane + 64) * NEDGES + e];
    }
    #pragma unroll
    for (int it = 0; it < NIT; ++it) {
        const int t = wid + it * 4;
        if (t < ci) {
            if (va[it] != 0.f) { inO[t] = lane;      inV[t] = va[it]; }
            if (vb[it] != 0.f) { inO[t] = lane + 64; inV[t] = vb[it]; }
        } else if (t < total) {
            const int s = t - ci;
            if (va[it] != 0.f) { outR[s] = lane;      outV[s] = va[it]; }
            if (vb[it] != 0.f) { outR[s] = lane + 64; outV[s] = vb[it]; }
        }
    }
    // fallback for total > 48 (statistically unreachable, kept for safety)
    for (int t = wid + NIT * 4; t < total; t += 4) {
        const bool isIn = t < ci;
        const int e = isIn ? inE[t] : outE[t - ci];
        const float* col = isIn ? Ro : Ri;
        const float v0f = col[lane * NEDGES + e];
        const float v1f = col[(lane + 64) * NEDGES + e];
        if (isIn) {
            if (v0f != 0.f) { inO[t] = lane;      inV[t] = v0f; }
            if (v1f != 0.f) { inO[t] = lane + 64; inV[t] = v1f; }
        } else {
            const int s = t - ci;
            if (v0f != 0.f) { outR[s] = lane;      outV[s] = v0f; }
            if (v1f != 0.f) { outR[s] = lane + 64; outV[s] = v1f; }
        }
    }
    __syncthreads();

    // ---- phase 3: accumulate angles via LDS atomics ----
    if (tid < ci) {
        const float wv = inW[tid] * inV[tid];
        const int   o  = inO[tid];
        #pragma unroll
        for (int k = 0; k < 5; ++k) atomicAdd(&Mang[k], wv * Xs[o * 5 + k]);
    } else if (tid >= 128 && tid - 128 < co) {
        const int   j  = tid - 128;
        const float wv = outW[j] * outV[j];
        const int   r  = outR[j];
        #pragma unroll
        for (int k = 0; k < 5; ++k) atomicAdd(&Mang[5 + k], wv * Xs[r * 5 + k]);
    }
    __syncthreads();
    if (wid >= 2) return;

    float c_, s_, t_, v0, v1, v2, v3;
#define CS(i)        __sincosf(0.5f * theta[i], &s_, &c_)

    if (wid == 0) {
        // ================= circuit A (qubits 0..7) =================
        float ic[8], is[8];
        #pragma unroll
        for (int q = 0; q < 8; ++q) __sincosf(0.5f * Mang[q], &is[q], &ic[q]);

        float lp = 1.f;
        #pragma unroll
        for (int q = 2; q < 8; ++q) lp *= ((lane >> (q - 2)) & 1) ? is[q] : ic[q];
        float r0 = lp * ic[0] * ic[1];
        float r1 = lp * is[0] * ic[1];
        float r2 = lp * ic[0] * is[1];
        float r3 = lp * is[0] * is[1];

#define RY_REG0      { t_ = r0; r0 = c_*t_ - s_*r1; r1 = fmaf(s_, t_, c_*r1); \
                       t_ = r2; r2 = c_*t_ - s_*r3; r3 = fmaf(s_, t_, c_*r3); }
#define RY_REG1      { t_ = r0; r0 = c_*t_ - s_*r2; r2 = fmaf(s_, t_, c_*r2); \
                       t_ = r1; r1 = c_*t_ - s_*r3; r3 = fmaf(s_, t_, c_*r3); }
#define RY_LANE_A(sh){ const float sg = ((lane >> (sh)) & 1) ? s_ : -s_;      \
                       v0 = __shfl_xor(r0, 1 << (sh), 64);                    \
                       v1 = __shfl_xor(r1, 1 << (sh), 64);                    \
                       v2 = __shfl_xor(r2, 1 << (sh), 64);                    \
                       v3 = __shfl_xor(r3, 1 << (sh), 64);                    \
                       r0 = fmaf(c_, r0, sg*v0); r1 = fmaf(c_, r1, sg*v1);    \
                       r2 = fmaf(c_, r2, sg*v2); r3 = fmaf(c_, r3, sg*v3); }
#define CX_LL_A(csh, tsh) { const bool p = (lane >> (csh)) & 1;               \
                       v0 = __shfl_xor(r0, 1 << (tsh), 64);                   \
                       v1 = __shfl_xor(r1, 1 << (tsh), 64);                   \
                       v2 = __shfl_xor(r2, 1 << (tsh), 64);                   \
                       v3 = __shfl_xor(r3, 1 << (tsh), 64);                   \
                       if (p) { r0 = v0; r1 = v1; r2 = v2; r3 = v3; } }

        CS(0);  RY_REG0;                     // R t0 q0
        CS(1);  RY_REG1;                     // R t1 q1
        t_ = r1; r1 = r3; r3 = t_;           // C(0->1): ctrl reg0, tgt reg1
        CS(2);  RY_LANE_A(0);                // R t2 q2
        CS(3);  RY_LANE_A(1);                // R t3 q3
        CX_LL_A(1, 0);                       // C(3->2)
        CS(4);  RY_LANE_A(2);                // R t4 q4
        CS(5);  RY_LANE_A(3);                // R t5 q5
        CX_LL_A(2, 3);                       // C(4->5)
        CS(6);  RY_LANE_A(4);                // R t6 q6
        CS(7);  RY_LANE_A(5);                // R t7 q7
        CX_LL_A(5, 4);                       // C(7->6)
        CS(15); RY_REG1;                     // R t15 q1
        CS(16); RY_LANE_A(0);                // R t16 q2
        r2 = __shfl_xor(r2, 1, 64);          // C(1->2): ctrl reg1, tgt lane0
        r3 = __shfl_xor(r3, 1, 64);
        CS(14); RY_LANE_A(3);                // R t14 q5
        CS(15); RY_LANE_A(4);                // R t15 q6
        CX_LL_A(4, 3);                       // C(6->5)
        CS(19); RY_LANE_A(0);                // R t19 q2
        CS(20); RY_LANE_A(3);                // R t20 q5
        CX_LL_A(0, 3);                       // C(2->5)
        CS(23); RY_LANE_A(3);                // R t23 q5
        CS(25); RY_REG0;                     // R t25 q0
        CS(26); RY_LANE_A(3);                // R t26 q5
        r1 = __shfl_xor(r1, 8, 64);          // C(0->5): ctrl reg0, tgt lane3
        r3 = __shfl_xor(r3, 8, 64);
        CS(29); RY_LANE_A(3);                // R t29 q5

        float zA = (r0*r0 + r1*r1 + r2*r2 + r3*r3) * (((lane >> 3) & 1) ? -1.f : 1.f);
        #pragma unroll
        for (int m = 1; m < 64; m <<= 1) zA += __shfl_xor(zA, m, 64);
        if (lane == 0) out[n * 2 + 0] = PI_F * (1.f - zA);
    } else {
        // ================= circuit B (qubits 8,9,10,11,13,14) =================
        float c8, s8, c9, s9, c10, s10, c11, s11, c13, s13, c14, s14;
        __sincosf(0.5f * Mang[8],  &s8,  &c8);
        __sincosf(0.5f * Mang[9],  &s9,  &c9);
        __sincosf(0.5f * Mang[10], &s10, &c10);
        __sincosf(0.5f * Mang[11], &s11, &c11);
        __sincosf(0.5f * Mang[13], &s13, &c13);
        __sincosf(0.5f * Mang[14], &s14, &c14);

        float b = ((lane >> 0) & 1) ? s8  : c8;
        b      *= ((lane >> 1) & 1) ? s9  : c9;
        b      *= ((lane >> 2) & 1) ? s10 : c10;
        b      *= ((lane >> 3) & 1) ? s11 : c11;
        b      *= ((lane >> 4) & 1) ? s13 : c13;
        b      *= ((lane >> 5) & 1) ? s14 : c14;

#define RY_B(sh)     { const float sg = ((lane >> (sh)) & 1) ? s_ : -s_;      \
                       v0 = __shfl_xor(b, 1 << (sh), 64);                     \
                       b = fmaf(c_, b, sg*v0); }
#define CX_B(csh, tsh) { v0 = __shfl_xor(b, 1 << (tsh), 64);                  \
                       if ((lane >> (csh)) & 1) b = v0; }

        CS(8);  RY_B(0);                     // R t8  q8
        CS(9);  RY_B(1);                     // R t9  q9
        CX_B(0, 1);                          // C(8->9)
        CS(10); RY_B(2);                     // R t10 q10
        CS(11); RY_B(3);                     // R t11 q11
        CX_B(3, 2);                          // C(11->10)
        CS(13); RY_B(4);                     // R t13 q13
        CX_B(0, 1);                          // C(8->9)
        CS(14); RY_B(5);                     // R t14 q14
        CS(16); RY_B(1);                     // R t16 q9
        CS(17); RY_B(2);                     // R t17 q10
        CX_B(1, 2);                          // C(9->10)
        CS(18); RY_B(4);                     // R t18 q13
        CS(19); RY_B(5);                     // R t19 q14
        CX_B(1, 2);                          // C(9->10)
        CS(21); RY_B(2);                     // R t21 q10
        CS(22); RY_B(4);                     // R t22 q13
        CX_B(4, 2);                          // C(13->10)
        CS(24); RY_B(2);                     // R t24 q10
        CS(27); RY_B(2);                     // R t27 q10
        CS(28); RY_B(5);                     // R t28 q14
        CX_B(5, 2);                          // C(14->10)
        CS(30); RY_B(2);                     // R t30 q10

        float zB = (b * b) * (((lane >> 2) & 1) ? -1.f : 1.f);
        #pragma unroll
        for (int m = 1; m < 64; m <<= 1) zB += __shfl_xor(zB, m, 64);
        if (lane == 0) out[n * 2 + 1] = PI_F * (1.f - zB);
    }
#undef CS
#undef RY_REG0
#undef RY_REG1
#undef RY_LANE_A
#undef CX_LL_A
#undef RY_B
#undef CX_B
}

extern "C" void kernel_launch(void* const* d_in, const int* in_sizes, int n_in,
                              void* d_out, int out_size, void* d_ws, size_t ws_size,
                              hipStream_t stream) {
    (void)in_sizes; (void)n_in; (void)d_ws; (void)ws_size; (void)out_size;
    const float* X     = (const float*)d_in[0];
    const float* ew    = (const float*)d_in[1];
    const float* Ri    = (const float*)d_in[2];
    const float* Ro    = (const float*)d_in[3];
    const float* theta = (const float*)d_in[4];
    float* out = (float*)d_out;

    nodenet_fused<<<NNODES, 256, 0, stream>>>(X, ew, Ri, Ro, theta, out);
}

// Round 8
// 11.896 us; speedup vs baseline: 1.2832x; 1.1500x over previous
//
#include <hip/hip_runtime.h>

namespace {
constexpr int NNODES = 128;
constexpr int NEDGES = 1024;
constexpr int NTH    = 512;    // 8 waves: halves phase-1/phase-2 serial depth
constexpr int CAP    = 96;     // max incident edges per node per direction
constexpr float PI_F = 3.14159265358979323846f;
}

// ---------------------------------------------------------------------------
// Fully fused, ONE dispatch (measured: ~10.6us fixed replay overhead +
// ~2.2us per extra dispatch dominate; kernel itself ~2us).
// One block per node, 8 waves. Ri/Ro columns are exact one-hots.
//  phase 1: scan own Ri/Ro rows (coalesced) -> incident edge lists
//  phase 2: dynamic column scans, one wave per slot (8 waves -> ~2 serial
//           round-trips) -> sender o(e) / receiver r(e) + column value
//  phase 3: angles M[15] via LDS atomics (few ops, contention trivial)
//  phase 4: wave 0 simulates sub-circuit A (qubits 0..7, 256 amps),
//           wave 1 simulates sub-circuit B (qubits 8,9,10,11,13,14, 64 amps).
//           Qubit 12 is unentangled & unmeasured -> dropped.
// A bit map: reg bit0=q0, reg bit1=q1, lane bit (q-2) = qubit q (q=2..7).
// B bit map: lane bits {0..5} = qubits {8,9,10,11,13,14}.
// ---------------------------------------------------------------------------
__global__ __launch_bounds__(NTH)
void nodenet_fused(const float* __restrict__ X,
                   const float* __restrict__ ew,
                   const float* __restrict__ Ri,
                   const float* __restrict__ Ro,
                   const float* __restrict__ theta,
                   float* __restrict__ out)
{
    __shared__ float Xs[NNODES * 5];
    __shared__ float Mang[15];
    __shared__ int   cin, cout;
    __shared__ int   inE[CAP];  __shared__ float inW[CAP];
    __shared__ int   inO[CAP];  __shared__ float inV[CAP];
    __shared__ int   outE[CAP]; __shared__ float outW[CAP];
    __shared__ int   outR[CAP]; __shared__ float outV[CAP];

    const int n = blockIdx.x, tid = threadIdx.x;
    const int lane = tid & 63, wid = tid >> 6;

    // ---- phase 0: stage X, init angle accumulators ----
    for (int i = tid; i < NNODES * 5; i += NTH) Xs[i] = X[i];
    if (tid < 10) Mang[tid] = 0.f;
    else if (tid < 15) Mang[tid] = X[n * 5 + (tid - 10)];
    if (tid == 0) { cin = 0; cout = 0; }
    __syncthreads();

    // ---- phase 1: scan own rows for incident edges (coalesced) ----
    #pragma unroll
    for (int j = 0; j < 2; ++j) {
        const int e = tid + j * NTH;
        const float riv = Ri[n * NEDGES + e];
        const float rov = Ro[n * NEDGES + e];
        if (riv != 0.f) {
            const int idx = atomicAdd(&cin, 1);
            if (idx < CAP) { inE[idx] = e; inW[idx] = riv * ew[e]; }
        }
        if (rov != 0.f) {
            const int idx = atomicAdd(&cout, 1);
            if (idx < CAP) { outE[idx] = e; outW[idx] = rov * ew[e]; }
        }
    }
    __syncthreads();

    // ---- phase 2: column scans, one wave per slot (dynamic, ~2 iters) ----
    const int ci = min(cin, CAP), co = min(cout, CAP);
    const int total = ci + co;
    for (int t = wid; t < total; t += 8) {
        const bool isIn = (t < ci);
        const int  e    = isIn ? inE[t] : outE[t - ci];
        const float* col = isIn ? Ro : Ri;     // opposite matrix's column
        const float v0 = col[lane * NEDGES + e];
        const float v1 = col[(lane + 64) * NEDGES + e];
        if (isIn) {
            if (lane == 0)  { inO[t] = 0; inV[t] = 0.f; }   // safety init
            if (v0 != 0.f)  { inO[t] = lane;      inV[t] = v0; }
            if (v1 != 0.f)  { inO[t] = lane + 64; inV[t] = v1; }
        } else {
            const int j = t - ci;
            if (lane == 0)  { outR[j] = 0; outV[j] = 0.f; }
            if (v0 != 0.f)  { outR[j] = lane;      outV[j] = v0; }
            if (v1 != 0.f)  { outR[j] = lane + 64; outV[j] = v1; }
        }
    }
    __syncthreads();

    // ---- phase 3: accumulate angles via LDS atomics ----
    if (tid < ci) {
        const float wv = inW[tid] * inV[tid];
        const int   o  = inO[tid];
        #pragma unroll
        for (int k = 0; k < 5; ++k) atomicAdd(&Mang[k], wv * Xs[o * 5 + k]);
    } else if (tid >= 128 && tid - 128 < co) {
        const int   j  = tid - 128;
        const float wv = outW[j] * outV[j];
        const int   r  = outR[j];
        #pragma unroll
        for (int k = 0; k < 5; ++k) atomicAdd(&Mang[5 + k], wv * Xs[r * 5 + k]);
    }
    __syncthreads();
    if (wid >= 2) return;

    float c_, s_, t_, v0, v1, v2, v3;
#define CS(i)        __sincosf(0.5f * theta[i], &s_, &c_)

    if (wid == 0) {
        // ================= circuit A (qubits 0..7) =================
        float ic[8], is[8];
        #pragma unroll
        for (int q = 0; q < 8; ++q) __sincosf(0.5f * Mang[q], &is[q], &ic[q]);

        float lp = 1.f;
        #pragma unroll
        for (int q = 2; q < 8; ++q) lp *= ((lane >> (q - 2)) & 1) ? is[q] : ic[q];
        float r0 = lp * ic[0] * ic[1];
        float r1 = lp * is[0] * ic[1];
        float r2 = lp * ic[0] * is[1];
        float r3 = lp * is[0] * is[1];

#define RY_REG0      { t_ = r0; r0 = c_*t_ - s_*r1; r1 = fmaf(s_, t_, c_*r1); \
                       t_ = r2; r2 = c_*t_ - s_*r3; r3 = fmaf(s_, t_, c_*r3); }
#define RY_REG1      { t_ = r0; r0 = c_*t_ - s_*r2; r2 = fmaf(s_, t_, c_*r2); \
                       t_ = r1; r1 = c_*t_ - s_*r3; r3 = fmaf(s_, t_, c_*r3); }
#define RY_LANE_A(sh){ const float sg = ((lane >> (sh)) & 1) ? s_ : -s_;      \
                       v0 = __shfl_xor(r0, 1 << (sh), 64);                    \
                       v1 = __shfl_xor(r1, 1 << (sh), 64);                    \
                       v2 = __shfl_xor(r2, 1 << (sh), 64);                    \
                       v3 = __shfl_xor(r3, 1 << (sh), 64);                    \
                       r0 = fmaf(c_, r0, sg*v0); r1 = fmaf(c_, r1, sg*v1);    \
                       r2 = fmaf(c_, r2, sg*v2); r3 = fmaf(c_, r3, sg*v3); }
#define CX_LL_A(csh, tsh) { const bool p = (lane >> (csh)) & 1;               \
                       v0 = __shfl_xor(r0, 1 << (tsh), 64);                   \
                       v1 = __shfl_xor(r1, 1 << (tsh), 64);                   \
                       v2 = __shfl_xor(r2, 1 << (tsh), 64);                   \
                       v3 = __shfl_xor(r3, 1 << (tsh), 64);                   \
                       if (p) { r0 = v0; r1 = v1; r2 = v2; r3 = v3; } }

        CS(0);  RY_REG0;                     // R t0 q0
        CS(1);  RY_REG1;                     // R t1 q1
        t_ = r1; r1 = r3; r3 = t_;           // C(0->1): ctrl reg0, tgt reg1
        CS(2);  RY_LANE_A(0);                // R t2 q2
        CS(3);  RY_LANE_A(1);                // R t3 q3
        CX_LL_A(1, 0);                       // C(3->2)
        CS(4);  RY_LANE_A(2);                // R t4 q4
        CS(5);  RY_LANE_A(3);                // R t5 q5
        CX_LL_A(2, 3);                       // C(4->5)
        CS(6);  RY_LANE_A(4);                // R t6 q6
        CS(7);  RY_LANE_A(5);                // R t7 q7
        CX_LL_A(5, 4);                       // C(7->6)
        CS(15); RY_REG1;                     // R t15 q1
        CS(16); RY_LANE_A(0);                // R t16 q2
        r2 = __shfl_xor(r2, 1, 64);          // C(1->2): ctrl reg1, tgt lane0
        r3 = __shfl_xor(r3, 1, 64);
        CS(14); RY_LANE_A(3);                // R t14 q5
        CS(15); RY_LANE_A(4);                // R t15 q6
        CX_LL_A(4, 3);                       // C(6->5)
        CS(19); RY_LANE_A(0);                // R t19 q2
        CS(20); RY_LANE_A(3);                // R t20 q5
        CX_LL_A(0, 3);                       // C(2->5)
        CS(23); RY_LANE_A(3);                // R t23 q5
        CS(25); RY_REG0;                     // R t25 q0
        CS(26); RY_LANE_A(3);                // R t26 q5
        r1 = __shfl_xor(r1, 8, 64);          // C(0->5): ctrl reg0, tgt lane3
        r3 = __shfl_xor(r3, 8, 64);
        CS(29); RY_LANE_A(3);                // R t29 q5

        float zA = (r0*r0 + r1*r1 + r2*r2 + r3*r3) * (((lane >> 3) & 1) ? -1.f : 1.f);
        #pragma unroll
        for (int m = 1; m < 64; m <<= 1) zA += __shfl_xor(zA, m, 64);
        if (lane == 0) out[n * 2 + 0] = PI_F * (1.f - zA);
    } else {
        // ================= circuit B (qubits 8,9,10,11,13,14) =================
        float c8, s8, c9, s9, c10, s10, c11, s11, c13, s13, c14, s14;
        __sincosf(0.5f * Mang[8],  &s8,  &c8);
        __sincosf(0.5f * Mang[9],  &s9,  &c9);
        __sincosf(0.5f * Mang[10], &s10, &c10);
        __sincosf(0.5f * Mang[11], &s11, &c11);
        __sincosf(0.5f * Mang[13], &s13, &c13);
        __sincosf(0.5f * Mang[14], &s14, &c14);

        float b = ((lane >> 0) & 1) ? s8  : c8;
        b      *= ((lane >> 1) & 1) ? s9  : c9;
        b      *= ((lane >> 2) & 1) ? s10 : c10;
        b      *= ((lane >> 3) & 1) ? s11 : c11;
        b      *= ((lane >> 4) & 1) ? s13 : c13;
        b      *= ((lane >> 5) & 1) ? s14 : c14;

#define RY_B(sh)     { const float sg = ((lane >> (sh)) & 1) ? s_ : -s_;      \
                       v0 = __shfl_xor(b, 1 << (sh), 64);                     \
                       b = fmaf(c_, b, sg*v0); }
#define CX_B(csh, tsh) { v0 = __shfl_xor(b, 1 << (tsh), 64);                  \
                       if ((lane >> (csh)) & 1) b = v0; }

        CS(8);  RY_B(0);                     // R t8  q8
        CS(9);  RY_B(1);                     // R t9  q9
        CX_B(0, 1);                          // C(8->9)
        CS(10); RY_B(2);                     // R t10 q10
        CS(11); RY_B(3);                     // R t11 q11
        CX_B(3, 2);                          // C(11->10)
        CS(13); RY_B(4);                     // R t13 q13
        CX_B(0, 1);                          // C(8->9)
        CS(14); RY_B(5);                     // R t14 q14
        CS(16); RY_B(1);                     // R t16 q9
        CS(17); RY_B(2);                     // R t17 q10
        CX_B(1, 2);                          // C(9->10)
        CS(18); RY_B(4);                     // R t18 q13
        CS(19); RY_B(5);                     // R t19 q14
        CX_B(1, 2);                          // C(9->10)
        CS(21); RY_B(2);                     // R t21 q10
        CS(22); RY_B(4);                     // R t22 q13
        CX_B(4, 2);                          // C(13->10)
        CS(24); RY_B(2);                     // R t24 q10
        CS(27); RY_B(2);                     // R t27 q10
        CS(28); RY_B(5);                     // R t28 q14
        CX_B(5, 2);                          // C(14->10)
        CS(30); RY_B(2);                     // R t30 q10

        float zB = (b * b) * (((lane >> 2) & 1) ? -1.f : 1.f);
        #pragma unroll
        for (int m = 1; m < 64; m <<= 1) zB += __shfl_xor(zB, m, 64);
        if (lane == 0) out[n * 2 + 1] = PI_F * (1.f - zB);
    }
#undef CS
#undef RY_REG0
#undef RY_REG1
#undef RY_LANE_A
#undef CX_LL_A
#undef RY_B
#undef CX_B
}

extern "C" void kernel_launch(void* const* d_in, const int* in_sizes, int n_in,
                              void* d_out, int out_size, void* d_ws, size_t ws_size,
                              hipStream_t stream) {
    (void)in_sizes; (void)n_in; (void)d_ws; (void)ws_size; (void)out_size;
    const float* X     = (const float*)d_in[0];
    const float* ew    = (const float*)d_in[1];
    const float* Ri    = (const float*)d_in[2];
    const float* Ro    = (const float*)d_in[3];
    const float* theta = (const float*)d_in[4];
    float* out = (float*)d_out;

    nodenet_fused<<<NNODES, NTH, 0, stream>>>(X, ew, Ri, Ro, theta, out);
}

// Round 9
// 11.172 us; speedup vs baseline: 1.3664x; 1.0648x over previous
//
#include <hip/hip_runtime.h>

namespace {
constexpr int NNODES = 128;
constexpr int NEDGES = 1024;
constexpr int NTH    = 1024;   // 16 waves: phase-2 completes in one iteration
constexpr int CAP    = 96;     // max incident edges per node per direction
constexpr float PI_F = 3.14159265358979323846f;
}

// ---------------------------------------------------------------------------
// Fully fused, ONE dispatch. Measured cost model: ~10.6us fixed graph-replay
// overhead + ~2.2us per extra dispatch; kernel itself ~1.5-2us, dominated by
// SERIAL cold-HBM round-trips (L2/L3 flushed by the harness's 268MB fills
// between replays). This version compresses the chain to 2 round-trips:
//  phase 0+1 (merged, one barrier): stage Xs AND scan own Ri/Ro rows
//             (independent coalesced loads -> one round-trip)
//  phase 2: column scans, one wave per incident edge, 16 waves -> 1 iter
//  phase 3: angles M[15] via LDS atomics
//  phase 4: wave 0 -> sub-circuit A (qubits 0..7, 256 amps: 4 regs x 64
//           lanes), wave 1 -> sub-circuit B (qubits 8,9,10,11,13,14, 64
//           amps). Qubit 12 unentangled & unmeasured -> dropped.
// A bit map: reg bit0=q0, reg bit1=q1, lane bit (q-2) = qubit q (q=2..7).
// B bit map: lane bits {0..5} = qubits {8,9,10,11,13,14}.
// ---------------------------------------------------------------------------
__global__ __launch_bounds__(NTH)
void nodenet_fused(const float* __restrict__ X,
                   const float* __restrict__ ew,
                   const float* __restrict__ Ri,
                   const float* __restrict__ Ro,
                   const float* __restrict__ theta,
                   float* __restrict__ out)
{
    __shared__ float Xs[NNODES * 5];
    __shared__ float Mang[15];
    __shared__ int   cin, cout;
    __shared__ int   inE[CAP];  __shared__ float inW[CAP];
    __shared__ int   inO[CAP];  __shared__ float inV[CAP];
    __shared__ int   outE[CAP]; __shared__ float outW[CAP];
    __shared__ int   outR[CAP]; __shared__ float outV[CAP];

    const int n = blockIdx.x, tid = threadIdx.x;
    const int lane = tid & 63, wid = tid >> 6;

    if (tid < 10) Mang[tid] = 0.f;
    else if (tid < 15) Mang[tid] = X[n * 5 + (tid - 10)];
    if (tid == 0) { cin = 0; cout = 0; }
    // no barrier needed before appends: counters zeroed by first wave's
    // scheduling? NOT guaranteed -> use a cheap s_barrier via __syncthreads.
    __syncthreads();

    // ---- phase 0+1 merged: stage Xs + own-row scan (one round-trip) ----
    {
        const int e = tid;                         // one edge per thread
        if (tid < NNODES * 5) Xs[tid] = X[tid];    // independent coalesced load
        const float we  = ew[e];                   // unconditional, coalesced
        const float riv = Ri[n * NEDGES + e];
        const float rov = Ro[n * NEDGES + e];
        if (riv != 0.f) {
            const int idx = atomicAdd(&cin, 1);
            if (idx < CAP) { inE[idx] = e; inW[idx] = riv * we; }
        }
        if (rov != 0.f) {
            const int idx = atomicAdd(&cout, 1);
            if (idx < CAP) { outE[idx] = e; outW[idx] = rov * we; }
        }
    }
    __syncthreads();

    // ---- phase 2: column scans, one wave per slot (16 waves -> 1 iter) ----
    const int ci = min(cin, CAP), co = min(cout, CAP);
    const int total = ci + co;
    for (int t = wid; t < total; t += 16) {
        const bool isIn = (t < ci);
        const int  e    = isIn ? inE[t] : outE[t - ci];
        const float* col = isIn ? Ro : Ri;     // opposite matrix's column
        const float v0 = col[lane * NEDGES + e];
        const float v1 = col[(lane + 64) * NEDGES + e];
        if (isIn) {
            if (lane == 0)  { inO[t] = 0; inV[t] = 0.f; }   // safety init
            if (v0 != 0.f)  { inO[t] = lane;      inV[t] = v0; }
            if (v1 != 0.f)  { inO[t] = lane + 64; inV[t] = v1; }
        } else {
            const int j = t - ci;
            if (lane == 0)  { outR[j] = 0; outV[j] = 0.f; }
            if (v0 != 0.f)  { outR[j] = lane;      outV[j] = v0; }
            if (v1 != 0.f)  { outR[j] = lane + 64; outV[j] = v1; }
        }
    }
    __syncthreads();

    // ---- phase 3: accumulate angles via LDS atomics ----
    if (tid < ci) {
        const float wv = inW[tid] * inV[tid];
        const int   o  = inO[tid];
        #pragma unroll
        for (int k = 0; k < 5; ++k) atomicAdd(&Mang[k], wv * Xs[o * 5 + k]);
    } else if (tid >= 128 && tid - 128 < co) {
        const int   j  = tid - 128;
        const float wv = outW[j] * outV[j];
        const int   r  = outR[j];
        #pragma unroll
        for (int k = 0; k < 5; ++k) atomicAdd(&Mang[5 + k], wv * Xs[r * 5 + k]);
    }
    __syncthreads();
    if (wid >= 2) return;

    float c_, s_, t_, v0, v1, v2, v3;
#define CS(i)        __sincosf(0.5f * theta[i], &s_, &c_)

    if (wid == 0) {
        // ================= circuit A (qubits 0..7) =================
        float ic[8], is[8];
        #pragma unroll
        for (int q = 0; q < 8; ++q) __sincosf(0.5f * Mang[q], &is[q], &ic[q]);

        float lp = 1.f;
        #pragma unroll
        for (int q = 2; q < 8; ++q) lp *= ((lane >> (q - 2)) & 1) ? is[q] : ic[q];
        float r0 = lp * ic[0] * ic[1];
        float r1 = lp * is[0] * ic[1];
        float r2 = lp * ic[0] * is[1];
        float r3 = lp * is[0] * is[1];

#define RY_REG0      { t_ = r0; r0 = c_*t_ - s_*r1; r1 = fmaf(s_, t_, c_*r1); \
                       t_ = r2; r2 = c_*t_ - s_*r3; r3 = fmaf(s_, t_, c_*r3); }
#define RY_REG1      { t_ = r0; r0 = c_*t_ - s_*r2; r2 = fmaf(s_, t_, c_*r2); \
                       t_ = r1; r1 = c_*t_ - s_*r3; r3 = fmaf(s_, t_, c_*r3); }
#define RY_LANE_A(sh){ const float sg = ((lane >> (sh)) & 1) ? s_ : -s_;      \
                       v0 = __shfl_xor(r0, 1 << (sh), 64);                    \
                       v1 = __shfl_xor(r1, 1 << (sh), 64);                    \
                       v2 = __shfl_xor(r2, 1 << (sh), 64);                    \
                       v3 = __shfl_xor(r3, 1 << (sh), 64);                    \
                       r0 = fmaf(c_, r0, sg*v0); r1 = fmaf(c_, r1, sg*v1);    \
                       r2 = fmaf(c_, r2, sg*v2); r3 = fmaf(c_, r3, sg*v3); }
#define CX_LL_A(csh, tsh) { const bool p = (lane >> (csh)) & 1;               \
                       v0 = __shfl_xor(r0, 1 << (tsh), 64);                   \
                       v1 = __shfl_xor(r1, 1 << (tsh), 64);                   \
                       v2 = __shfl_xor(r2, 1 << (tsh), 64);                   \
                       v3 = __shfl_xor(r3, 1 << (tsh), 64);                   \
                       if (p) { r0 = v0; r1 = v1; r2 = v2; r3 = v3; } }

        CS(0);  RY_REG0;                     // R t0 q0
        CS(1);  RY_REG1;                     // R t1 q1
        t_ = r1; r1 = r3; r3 = t_;           // C(0->1): ctrl reg0, tgt reg1
        CS(2);  RY_LANE_A(0);                // R t2 q2
        CS(3);  RY_LANE_A(1);                // R t3 q3
        CX_LL_A(1, 0);                       // C(3->2)
        CS(4);  RY_LANE_A(2);                // R t4 q4
        CS(5);  RY_LANE_A(3);                // R t5 q5
        CX_LL_A(2, 3);                       // C(4->5)
        CS(6);  RY_LANE_A(4);                // R t6 q6
        CS(7);  RY_LANE_A(5);                // R t7 q7
        CX_LL_A(5, 4);                       // C(7->6)
        CS(15); RY_REG1;                     // R t15 q1
        CS(16); RY_LANE_A(0);                // R t16 q2
        r2 = __shfl_xor(r2, 1, 64);          // C(1->2): ctrl reg1, tgt lane0
        r3 = __shfl_xor(r3, 1, 64);
        CS(14); RY_LANE_A(3);                // R t14 q5
        CS(15); RY_LANE_A(4);                // R t15 q6
        CX_LL_A(4, 3);                       // C(6->5)
        CS(19); RY_LANE_A(0);                // R t19 q2
        CS(20); RY_LANE_A(3);                // R t20 q5
        CX_LL_A(0, 3);                       // C(2->5)
        CS(23); RY_LANE_A(3);                // R t23 q5
        CS(25); RY_REG0;                     // R t25 q0
        CS(26); RY_LANE_A(3);                // R t26 q5
        r1 = __shfl_xor(r1, 8, 64);          // C(0->5): ctrl reg0, tgt lane3
        r3 = __shfl_xor(r3, 8, 64);
        CS(29); RY_LANE_A(3);                // R t29 q5

        float zA = (r0*r0 + r1*r1 + r2*r2 + r3*r3) * (((lane >> 3) & 1) ? -1.f : 1.f);
        #pragma unroll
        for (int m = 1; m < 64; m <<= 1) zA += __shfl_xor(zA, m, 64);
        if (lane == 0) out[n * 2 + 0] = PI_F * (1.f - zA);
    } else {
        // ================= circuit B (qubits 8,9,10,11,13,14) =================
        float c8, s8, c9, s9, c10, s10, c11, s11, c13, s13, c14, s14;
        __sincosf(0.5f * Mang[8],  &s8,  &c8);
        __sincosf(0.5f * Mang[9],  &s9,  &c9);
        __sincosf(0.5f * Mang[10], &s10, &c10);
        __sincosf(0.5f * Mang[11], &s11, &c11);
        __sincosf(0.5f * Mang[13], &s13, &c13);
        __sincosf(0.5f * Mang[14], &s14, &c14);

        float b = ((lane >> 0) & 1) ? s8  : c8;
        b      *= ((lane >> 1) & 1) ? s9  : c9;
        b      *= ((lane >> 2) & 1) ? s10 : c10;
        b      *= ((lane >> 3) & 1) ? s11 : c11;
        b      *= ((lane >> 4) & 1) ? s13 : c13;
        b      *= ((lane >> 5) & 1) ? s14 : c14;

#define RY_B(sh)     { const float sg = ((lane >> (sh)) & 1) ? s_ : -s_;      \
                       v0 = __shfl_xor(b, 1 << (sh), 64);                     \
                       b = fmaf(c_, b, sg*v0); }
#define CX_B(csh, tsh) { v0 = __shfl_xor(b, 1 << (tsh), 64);                  \
                       if ((lane >> (csh)) & 1) b = v0; }

        CS(8);  RY_B(0);                     // R t8  q8
        CS(9);  RY_B(1);                     // R t9  q9
        CX_B(0, 1);                          // C(8->9)
        CS(10); RY_B(2);                     // R t10 q10
        CS(11); RY_B(3);                     // R t11 q11
        CX_B(3, 2);                          // C(11->10)
        CS(13); RY_B(4);                     // R t13 q13
        CX_B(0, 1);                          // C(8->9)
        CS(14); RY_B(5);                     // R t14 q14
        CS(16); RY_B(1);                     // R t16 q9
        CS(17); RY_B(2);                     // R t17 q10
        CX_B(1, 2);                          // C(9->10)
        CS(18); RY_B(4);                     // R t18 q13
        CS(19); RY_B(5);                     // R t19 q14
        CX_B(1, 2);                          // C(9->10)
        CS(21); RY_B(2);                     // R t21 q10
        CS(22); RY_B(4);                     // R t22 q13
        CX_B(4, 2);                          // C(13->10)
        CS(24); RY_B(2);                     // R t24 q10
        CS(27); RY_B(2);                     // R t27 q10
        CS(28); RY_B(5);                     // R t28 q14
        CX_B(5, 2);                          // C(14->10)
        CS(30); RY_B(2);                     // R t30 q10

        float zB = (b * b) * (((lane >> 2) & 1) ? -1.f : 1.f);
        #pragma unroll
        for (int m = 1; m < 64; m <<= 1) zB += __shfl_xor(zB, m, 64);
        if (lane == 0) out[n * 2 + 1] = PI_F * (1.f - zB);
    }
#undef CS
#undef RY_REG0
#undef RY_REG1
#undef RY_LANE_A
#undef CX_LL_A
#undef RY_B
#undef CX_B
}

extern "C" void kernel_launch(void* const* d_in, const int* in_sizes, int n_in,
                              void* d_out, int out_size, void* d_ws, size_t ws_size,
                              hipStream_t stream) {
    (void)in_sizes; (void)n_in; (void)d_ws; (void)ws_size; (void)out_size;
    const float* X     = (const float*)d_in[0];
    const float* ew    = (const float*)d_in[1];
    const float* Ri    = (const float*)d_in[2];
    const float* Ro    = (const float*)d_in[3];
    const float* theta = (const float*)d_in[4];
    float* out = (float*)d_out;

    nodenet_fused<<<NNODES, NTH, 0, stream>>>(X, ew, Ri, Ro, theta, out);
}

// Round 10
// 10.969 us; speedup vs baseline: 1.3916x; 1.0184x over previous
//
#include <hip/hip_runtime.h>

namespace {
constexpr int NNODES = 128;
constexpr int NEDGES = 1024;
constexpr int NTH    = 1024;   // 16 waves: column scan completes in one iter
constexpr int CAP    = 96;     // max incident edges per node per direction
constexpr float PI_F = 3.14159265358979323846f;
}

// ---------------------------------------------------------------------------
// Fully fused, ONE dispatch. Cost model (fit over rounds 3-9): ~9.5-10us
// fixed graph-replay overhead + ~2.2us per extra dispatch; kernel ~1.3-1.7us
// = 2 structurally-serial cold-HBM trips (L2/L3 flushed by harness's 268MB
// fills between replays) + circuit. Critical chain this version:
//  barrier0 (init cin/cout)
//  trip 1: stage Xs + own Ri/Ro row scan + ew (all coalesced, one trip)
//  barrier1
//  trip 2: one wave per incident edge scans the opposite matrix's column
//          (one-hot) -> hit lane directly atomicAdds its 5 angle terms
//          into Mang (Xs already in LDS)  [phases 2+3 merged]
//  barrier2
//  wave 0 -> sub-circuit A (qubits 0..7, 256 amps: 4 regs x 64 lanes)
//  wave 1 -> sub-circuit B (qubits 8,9,10,11,13,14, 64 amps)
//  Qubit 12 unentangled & unmeasured -> dropped.
// A bit map: reg bit0=q0, reg bit1=q1, lane bit (q-2) = qubit q (q=2..7).
// B bit map: lane bits {0..5} = qubits {8,9,10,11,13,14}.
// ---------------------------------------------------------------------------
__global__ __launch_bounds__(NTH)
void nodenet_fused(const float* __restrict__ X,
                   const float* __restrict__ ew,
                   const float* __restrict__ Ri,
                   const float* __restrict__ Ro,
                   const float* __restrict__ theta,
                   float* __restrict__ out)
{
    __shared__ float Xs[NNODES * 5];
    __shared__ float Mang[15];
    __shared__ int   cin, cout;
    __shared__ int   inE[CAP];  __shared__ float inW[CAP];
    __shared__ int   outE[CAP]; __shared__ float outW[CAP];

    const int n = blockIdx.x, tid = threadIdx.x;
    const int lane = tid & 63, wid = tid >> 6;

    if (tid < 10) Mang[tid] = 0.f;
    else if (tid < 15) Mang[tid] = X[n * 5 + (tid - 10)];
    if (tid == 0) { cin = 0; cout = 0; }
    __syncthreads();

    // ---- trip 1: stage Xs + own-row scan (one coalesced round-trip) ----
    {
        const int e = tid;                         // one edge per thread
        if (tid < NNODES * 5) Xs[tid] = X[tid];    // independent coalesced load
        const float we  = ew[e];                   // unconditional, coalesced
        const float riv = Ri[n * NEDGES + e];
        const float rov = Ro[n * NEDGES + e];
        if (riv != 0.f) {
            const int idx = atomicAdd(&cin, 1);
            if (idx < CAP) { inE[idx] = e; inW[idx] = riv * we; }
        }
        if (rov != 0.f) {
            const int idx = atomicAdd(&cout, 1);
            if (idx < CAP) { outE[idx] = e; outW[idx] = rov * we; }
        }
    }
    __syncthreads();

    // ---- trip 2: column scan + direct angle accumulation (merged) ----
    const int ci = min(cin, CAP), co = min(cout, CAP);
    const int total = ci + co;
    for (int t = wid; t < total; t += 16) {
        const bool isIn = (t < ci);
        const int   e   = isIn ? inE[t] : outE[t - ci];
        const float wgt = isIn ? inW[t] : outW[t - ci];
        const float* col = isIn ? Ro : Ri;     // opposite matrix's column
        const float v0 = col[lane * NEDGES + e];
        const float v1 = col[(lane + 64) * NEDGES + e];
        int m = -1; float vv = 0.f;
        if (v0 != 0.f) { m = lane;      vv = v0; }
        if (v1 != 0.f) { m = lane + 64; vv = v1; }
        if (m >= 0) {                           // the single hit lane
            const float wv  = wgt * vv;
            const int  base = isIn ? 0 : 5;
            #pragma unroll
            for (int k = 0; k < 5; ++k)
                atomicAdd(&Mang[base + k], wv * Xs[m * 5 + k]);
        }
    }
    __syncthreads();
    if (wid >= 2) return;

    float c_, s_, t_, v0, v1, v2, v3;
#define CS(i)        __sincosf(0.5f * theta[i], &s_, &c_)

    if (wid == 0) {
        // ================= circuit A (qubits 0..7) =================
        float ic[8], is[8];
        #pragma unroll
        for (int q = 0; q < 8; ++q) __sincosf(0.5f * Mang[q], &is[q], &ic[q]);

        float lp = 1.f;
        #pragma unroll
        for (int q = 2; q < 8; ++q) lp *= ((lane >> (q - 2)) & 1) ? is[q] : ic[q];
        float r0 = lp * ic[0] * ic[1];
        float r1 = lp * is[0] * ic[1];
        float r2 = lp * ic[0] * is[1];
        float r3 = lp * is[0] * is[1];

#define RY_REG0      { t_ = r0; r0 = c_*t_ - s_*r1; r1 = fmaf(s_, t_, c_*r1); \
                       t_ = r2; r2 = c_*t_ - s_*r3; r3 = fmaf(s_, t_, c_*r3); }
#define RY_REG1      { t_ = r0; r0 = c_*t_ - s_*r2; r2 = fmaf(s_, t_, c_*r2); \
                       t_ = r1; r1 = c_*t_ - s_*r3; r3 = fmaf(s_, t_, c_*r3); }
#define RY_LANE_A(sh){ const float sg = ((lane >> (sh)) & 1) ? s_ : -s_;      \
                       v0 = __shfl_xor(r0, 1 << (sh), 64);                    \
                       v1 = __shfl_xor(r1, 1 << (sh), 64);                    \
                       v2 = __shfl_xor(r2, 1 << (sh), 64);                    \
                       v3 = __shfl_xor(r3, 1 << (sh), 64);                    \
                       r0 = fmaf(c_, r0, sg*v0); r1 = fmaf(c_, r1, sg*v1);    \
                       r2 = fmaf(c_, r2, sg*v2); r3 = fmaf(c_, r3, sg*v3); }
#define CX_LL_A(csh, tsh) { const bool p = (lane >> (csh)) & 1;               \
                       v0 = __shfl_xor(r0, 1 << (tsh), 64);                   \
                       v1 = __shfl_xor(r1, 1 << (tsh), 64);                   \
                       v2 = __shfl_xor(r2, 1 << (tsh), 64);                   \
                       v3 = __shfl_xor(r3, 1 << (tsh), 64);                   \
                       if (p) { r0 = v0; r1 = v1; r2 = v2; r3 = v3; } }

        CS(0);  RY_REG0;                     // R t0 q0
        CS(1);  RY_REG1;                     // R t1 q1
        t_ = r1; r1 = r3; r3 = t_;           // C(0->1): ctrl reg0, tgt reg1
        CS(2);  RY_LANE_A(0);                // R t2 q2
        CS(3);  RY_LANE_A(1);                // R t3 q3
        CX_LL_A(1, 0);                       // C(3->2)
        CS(4);  RY_LANE_A(2);                // R t4 q4
        CS(5);  RY_LANE_A(3);                // R t5 q5
        CX_LL_A(2, 3);                       // C(4->5)
        CS(6);  RY_LANE_A(4);                // R t6 q6
        CS(7);  RY_LANE_A(5);                // R t7 q7
        CX_LL_A(5, 4);                       // C(7->6)
        CS(15); RY_REG1;                     // R t15 q1
        CS(16); RY_LANE_A(0);                // R t16 q2
        r2 = __shfl_xor(r2, 1, 64);          // C(1->2): ctrl reg1, tgt lane0
        r3 = __shfl_xor(r3, 1, 64);
        CS(14); RY_LANE_A(3);                // R t14 q5
        CS(15); RY_LANE_A(4);                // R t15 q6
        CX_LL_A(4, 3);                       // C(6->5)
        CS(19); RY_LANE_A(0);                // R t19 q2
        CS(20); RY_LANE_A(3);                // R t20 q5
        CX_LL_A(0, 3);                       // C(2->5)
        CS(23); RY_LANE_A(3);                // R t23 q5
        CS(25); RY_REG0;                     // R t25 q0
        CS(26); RY_LANE_A(3);                // R t26 q5
        r1 = __shfl_xor(r1, 8, 64);          // C(0->5): ctrl reg0, tgt lane3
        r3 = __shfl_xor(r3, 8, 64);
        CS(29); RY_LANE_A(3);                // R t29 q5

        float zA = (r0*r0 + r1*r1 + r2*r2 + r3*r3) * (((lane >> 3) & 1) ? -1.f : 1.f);
        #pragma unroll
        for (int m = 1; m < 64; m <<= 1) zA += __shfl_xor(zA, m, 64);
        if (lane == 0) out[n * 2 + 0] = PI_F * (1.f - zA);
    } else {
        // ================= circuit B (qubits 8,9,10,11,13,14) =================
        float c8, s8, c9, s9, c10, s10, c11, s11, c13, s13, c14, s14;
        __sincosf(0.5f * Mang[8],  &s8,  &c8);
        __sincosf(0.5f * Mang[9],  &s9,  &c9);
        __sincosf(0.5f * Mang[10], &s10, &c10);
        __sincosf(0.5f * Mang[11], &s11, &c11);
        __sincosf(0.5f * Mang[13], &s13, &c13);
        __sincosf(0.5f * Mang[14], &s14, &c14);

        float b = ((lane >> 0) & 1) ? s8  : c8;
        b      *= ((lane >> 1) & 1) ? s9  : c9;
        b      *= ((lane >> 2) & 1) ? s10 : c10;
        b      *= ((lane >> 3) & 1) ? s11 : c11;
        b      *= ((lane >> 4) & 1) ? s13 : c13;
        b      *= ((lane >> 5) & 1) ? s14 : c14;

#define RY_B(sh)     { const float sg = ((lane >> (sh)) & 1) ? s_ : -s_;      \
                       v0 = __shfl_xor(b, 1 << (sh), 64);                     \
                       b = fmaf(c_, b, sg*v0); }
#define CX_B(csh, tsh) { v0 = __shfl_xor(b, 1 << (tsh), 64);                  \
                       if ((lane >> (csh)) & 1) b = v0; }

        CS(8);  RY_B(0);                     // R t8  q8
        CS(9);  RY_B(1);                     // R t9  q9
        CX_B(0, 1);                          // C(8->9)
        CS(10); RY_B(2);                     // R t10 q10
        CS(11); RY_B(3);                     // R t11 q11
        CX_B(3, 2);                          // C(11->10)
        CS(13); RY_B(4);                     // R t13 q13
        CX_B(0, 1);                          // C(8->9)
        CS(14); RY_B(5);                     // R t14 q14
        CS(16); RY_B(1);                     // R t16 q9
        CS(17); RY_B(2);                     // R t17 q10
        CX_B(1, 2);                          // C(9->10)
        CS(18); RY_B(4);                     // R t18 q13
        CS(19); RY_B(5);                     // R t19 q14
        CX_B(1, 2);                          // C(9->10)
        CS(21); RY_B(2);                     // R t21 q10
        CS(22); RY_B(4);                     // R t22 q13
        CX_B(4, 2);                          // C(13->10)
        CS(24); RY_B(2);                     // R t24 q10
        CS(27); RY_B(2);                     // R t27 q10
        CS(28); RY_B(5);                     // R t28 q14
        CX_B(5, 2);                          // C(14->10)
        CS(30); RY_B(2);                     // R t30 q10

        float zB = (b * b) * (((lane >> 2) & 1) ? -1.f : 1.f);
        #pragma unroll
        for (int m = 1; m < 64; m <<= 1) zB += __shfl_xor(zB, m, 64);
        if (lane == 0) out[n * 2 + 1] = PI_F * (1.f - zB);
    }
#undef CS
#undef RY_REG0
#undef RY_REG1
#undef RY_LANE_A
#undef CX_LL_A
#undef RY_B
#undef CX_B
}

extern "C" void kernel_launch(void* const* d_in, const int* in_sizes, int n_in,
                              void* d_out, int out_size, void* d_ws, size_t ws_size,
                              hipStream_t stream) {
    (void)in_sizes; (void)n_in; (void)d_ws; (void)ws_size; (void)out_size;
    const float* X     = (const float*)d_in[0];
    const float* ew    = (const float*)d_in[1];
    const float* Ri    = (const float*)d_in[2];
    const float* Ro    = (const float*)d_in[3];
    const float* theta = (const float*)d_in[4];
    float* out = (float*)d_out;

    nodenet_fused<<<NNODES, NTH, 0, stream>>>(X, ew, Ri, Ro, theta, out);
}